// Round 1
// baseline (136.716 us; speedup 1.0000x reference)
//
#include <hip/hip_runtime.h>
#include <math.h>

// SupCR loss, MI355X. Round 9:
//  - prep_sort_kernel: fuses bf16-split/norms (256 blocks, 8 rows each) with a
//    parallel RANK sort of the 1024 labels (2 blocks); replaces the serial
//    single-block bitonic sort (55 barrier stages on one CU).
//  - GEMM: 64x64 tiles over the full lower triangle -> 528 blocks (was 272
//    128x64 blocks, ~1.06/CU). Better CU balance + co-resident blocks to
//    hide the per-iteration staging latency.
//  - row_kernel: 512 threads, 4 elements/thread. Halves the serial dependent
//    LDS binary-search chain per thread and doubles waves/CU (16 -> 32).
// Math identical to round 8 (fp32 scans with +64 exponent bias).

#define NN 2048      // N = B*V
#define BB 1024      // B
#define DD 512       // D
#define NT 256
#define NEGINF (-INFINITY)
#define CS 64.0f     // exponent pre-scale bias

typedef short s16x8 __attribute__((ext_vector_type(8)));
typedef float f32x4 __attribute__((ext_vector_type(4)));

// row i of the virtual cf matrix lives at F + ((i%B)*2 + i/B)*D
__device__ __forceinline__ const float* cf_row(const float* F, int i) {
    return F + ((size_t)(i & (BB - 1)) * 2 + (size_t)(i >> 10)) * DD;
}

__device__ __forceinline__ unsigned bf_rne(float x) {
    const unsigned u = __float_as_uint(x);
    return (u + 0x7FFFu + ((u >> 16) & 1u)) >> 16;
}
__device__ __forceinline__ float bf_val(unsigned h) {
    return __uint_as_float(h << 16);
}

// ---------------- kernel 0: fused prep (blocks 0..255) + rank sort (256,257) ----
__global__ __launch_bounds__(512) void prep_sort_kernel(const float* __restrict__ F,
                                                        const float* __restrict__ labels,
                                                        ushort* __restrict__ Ahi,
                                                        ushort* __restrict__ Alo,
                                                        float* __restrict__ sq,
                                                        float* __restrict__ slab,
                                                        int* __restrict__ sj) {
    __shared__ float lab[BB];
    const int blk = blockIdx.x;
    const int t = threadIdx.x;

    if (blk < 256) {
        // ---- prep: 8 rows per block, one row per wave ----
        const int lane = t & 63;
        const int w = t >> 6;
        const int i = blk * 8 + w;
        const float* src = cf_row(F, i);
        const float4 v0 = reinterpret_cast<const float4*>(src)[lane];
        const float4 v1 = reinterpret_cast<const float4*>(src)[lane + 64];
        float ss = v0.x * v0.x + v0.y * v0.y + v0.z * v0.z + v0.w * v0.w
                 + v1.x * v1.x + v1.y * v1.y + v1.z * v1.z + v1.w * v1.w;
        #pragma unroll
        for (int st = 32; st > 0; st >>= 1) ss += __shfl_down(ss, st);
        if (lane == 0) sq[i] = ss;

        const float a[8] = {v0.x, v0.y, v0.z, v0.w, v1.x, v1.y, v1.z, v1.w};
        ushort h[8], l[8];
        #pragma unroll
        for (int e = 0; e < 8; ++e) {
            const unsigned hb = bf_rne(a[e]);
            h[e] = (ushort)hb;
            l[e] = (ushort)bf_rne(a[e] - bf_val(hb));
        }
        const size_t base = (size_t)i * DD;
        *reinterpret_cast<ushort4*>(&Ahi[base + lane * 4])       = make_ushort4(h[0], h[1], h[2], h[3]);
        *reinterpret_cast<ushort4*>(&Ahi[base + 256 + lane * 4]) = make_ushort4(h[4], h[5], h[6], h[7]);
        *reinterpret_cast<ushort4*>(&Alo[base + lane * 4])       = make_ushort4(l[0], l[1], l[2], l[3]);
        *reinterpret_cast<ushort4*>(&Alo[base + 256 + lane * 4]) = make_ushort4(l[4], l[5], l[6], l[7]);
    } else {
        // ---- rank sort: block 256 -> elements 0..511, block 257 -> 512..1023 ----
        lab[t] = labels[t];
        lab[t + 512] = labels[t + 512];
        __syncthreads();
        const int e = (blk - 256) * 512 + t;
        const float li = lab[e];
        int rank = 0;
        const float4* l4 = reinterpret_cast<const float4*>(lab);
        #pragma unroll 4
        for (int j = 0; j < BB / 4; ++j) {
            const float4 v = l4[j];
            const int j0 = j * 4;
            rank += (v.x < li) || (v.x == li && (j0 + 0) < e);
            rank += (v.y < li) || (v.y == li && (j0 + 1) < e);
            rank += (v.z < li) || (v.z == li && (j0 + 2) < e);
            rank += (v.w < li) || (v.w == li && (j0 + 3) < e);
        }
        slab[2 * rank]     = li;
        slab[2 * rank + 1] = li;
        sj[2 * rank]     = e;
        sj[2 * rank + 1] = e + BB;
    }
}

// ---------------- kernel 1: MFMA dist, symmetric, 64x64 lower-tri tiles ------
#define TM 64
#define TN 64
#define TK 32
__global__ __launch_bounds__(256) void gemm_dist_kernel(const ushort* __restrict__ Ahi,
                                                        const ushort* __restrict__ Alo,
                                                        const float* __restrict__ sq,
                                                        const int* __restrict__ sj,
                                                        float* __restrict__ distp) {
    __shared__ ushort Ah[4][TM][8];
    __shared__ ushort Al[4][TM][8];
    __shared__ ushort Bh[4][TN][8];
    __shared__ ushort Bl[4][TN][8];
    __shared__ int   sjcA[TM];
    __shared__ int   sjcB[TN];
    __shared__ float sqA[TM];
    __shared__ float sqB[TN];

    const int t = threadIdx.x;
    const int lane = t & 63;
    const int w = t >> 6;

    // tile id -> (by, bx) over lower triangle incl. diagonal: id = by*(by+1)/2 + bx
    const int id = blockIdx.x;
    int by = (int)((__fsqrt_rn(8.0f * (float)id + 1.0f) - 1.0f) * 0.5f);
    while ((by + 1) * (by + 2) / 2 <= id) ++by;
    while (by * (by + 1) / 2 > id) --by;
    const int bx = id - by * (by + 1) / 2;      // 0 .. by
    const int row0 = by * TM;
    const int col0 = bx * TN;
    const bool below = (bx < by);               // strictly below diagonal square

    if (t < TM) {
        const int s = sj[row0 + t];
        sjcA[t] = s; sqA[t] = sq[s];
    } else if (t < TM + TN) {
        const int u = t - TM;
        const int s = sj[col0 + u];
        sjcB[u] = s; sqB[u] = sq[s];
    }
    __syncthreads();
    const int rr = t >> 2;
    const int cq = t & 3;
    const size_t gA = (size_t)sjcA[rr] * DD + cq * 8;
    const size_t gB = (size_t)sjcB[rr] * DD + cq * 8;

    f32x4 acc[4] = {};
    const int m = lane & 15;
    const int q = lane >> 4;

    for (int kt = 0; kt < DD / TK; ++kt) {
        __syncthreads();
        const size_t ko = (size_t)kt * TK;
        *reinterpret_cast<int4*>(&Ah[cq][rr][0]) = *reinterpret_cast<const int4*>(&Ahi[gA + ko]);
        *reinterpret_cast<int4*>(&Al[cq][rr][0]) = *reinterpret_cast<const int4*>(&Alo[gA + ko]);
        *reinterpret_cast<int4*>(&Bh[cq][rr][0]) = *reinterpret_cast<const int4*>(&Ahi[gB + ko]);
        *reinterpret_cast<int4*>(&Bl[cq][rr][0]) = *reinterpret_cast<const int4*>(&Alo[gB + ko]);
        __syncthreads();

        const s16x8 fah = *reinterpret_cast<const s16x8*>(&Ah[q][w * 16 + m][0]);
        const s16x8 fal = *reinterpret_cast<const s16x8*>(&Al[q][w * 16 + m][0]);
        #pragma unroll
        for (int nt = 0; nt < 4; ++nt) {
            const s16x8 fbh = *reinterpret_cast<const s16x8*>(&Bh[q][nt * 16 + m][0]);
            const s16x8 fbl = *reinterpret_cast<const s16x8*>(&Bl[q][nt * 16 + m][0]);
            acc[nt] = __builtin_amdgcn_mfma_f32_16x16x32_bf16(fah, fbh, acc[nt], 0, 0, 0);
            acc[nt] = __builtin_amdgcn_mfma_f32_16x16x32_bf16(fah, fbl, acc[nt], 0, 0, 0);
            acc[nt] = __builtin_amdgcn_mfma_f32_16x16x32_bf16(fal, fbh, acc[nt], 0, 0, 0);
        }
    }

    const int lr0 = w * 16 + q * 4;
    #pragma unroll
    for (int nt = 0; nt < 4; ++nt) {
        const int lc = nt * 16 + m;
        float o[4];
        #pragma unroll
        for (int r = 0; r < 4; ++r) {
            const float d2 = sqA[lr0 + r] + sqB[lc] - 2.0f * acc[nt][r];
            o[r] = (d2 > 0.f) ? sqrtf(d2) : 0.f;
        }
        #pragma unroll
        for (int r = 0; r < 4; ++r)
            distp[(size_t)(row0 + lr0 + r) * NN + col0 + lc] = o[r];
        if (below) {
            const float4 o4 = make_float4(o[0], o[1], o[2], o[3]);
            *reinterpret_cast<float4*>(&distp[(size_t)(col0 + lc) * NN + row0 + lr0]) = o4;
        }
    }
}

// ---------------- kernel 2: row-pair scans + shared window lookup ----------
// first idx in [lo,hi) with key[idx] >= d (right segment: keys non-decreasing)
__device__ __forceinline__ int bs_right(const float* key, float d, int lo, int hi) {
    while (lo < hi) {
        const int mid = (lo + hi) >> 1;
        if (key[mid] >= d) hi = mid; else lo = mid + 1;
    }
    return lo;
}
// first idx in [lo,hi) with key[idx] < d (left segment: keys non-increasing)
__device__ __forceinline__ int bs_left(const float* key, float d, int lo, int hi) {
    while (lo < hi) {
        const int mid = (lo + hi) >> 1;
        if (key[mid] < d) hi = mid; else lo = mid + 1;
    }
    return lo;
}

__global__ __launch_bounds__(512) void row_kernel(const float* __restrict__ distp,
                                                  const float* __restrict__ slab,
                                                  double* __restrict__ rowval) {
    __shared__ float key[NN];
    __shared__ float Pf[NN];
    __shared__ float Sf[NN + 1];
    __shared__ float wmxA[8], wmxB[8], wps[8], wss[8];
    __shared__ double wDA[8], wLA[8], wDB[8], wLB[8];

    const int pr = blockIdx.x;           // pair index
    const int rA = 2 * pr, rB = 2 * pr + 1;
    const int t = threadIdx.x;
    const int lane = t & 63;
    const int w = t >> 6;
    const float x = slab[rA];
    const float negInvT = -1.0f / 0.07f;
    const float* drowA = &distp[(size_t)rA * NN];
    const float* drowB = &distp[(size_t)rB * NN];

    // ---- keys (shared by both rows), vals for both rows, row maxima ----
    {
        const float4 l4 = reinterpret_cast<const float4*>(slab)[t];
        key[t * 4 + 0] = fabsf(l4.x - x);
        key[t * 4 + 1] = fabsf(l4.y - x);
        key[t * 4 + 2] = fabsf(l4.z - x);
        key[t * 4 + 3] = fabsf(l4.w - x);
    }
    const int cb = t * 4;
    float vA[4], vB[4];
    double dsumA = 0.0, dsumB = 0.0;
    float mxA = NEGINF, mxB = NEGINF;
    {
        const float4 a4 = reinterpret_cast<const float4*>(drowA)[t];
        const float4 b4 = reinterpret_cast<const float4*>(drowB)[t];
        const float av[4] = {a4.x, a4.y, a4.z, a4.w};
        const float bv[4] = {b4.x, b4.y, b4.z, b4.w};
        #pragma unroll
        for (int c = 0; c < 4; ++c) {
            const int pc = cb + c;
            if (pc == rA) vA[c] = NEGINF;
            else { const float vv = av[c] * negInvT; vA[c] = vv; mxA = fmaxf(mxA, vv); dsumA += (double)av[c]; }
            if (pc == rB) vB[c] = NEGINF;
            else { const float vv = bv[c] * negInvT; vB[c] = vv; mxB = fmaxf(mxB, vv); dsumB += (double)bv[c]; }
        }
    }
    #pragma unroll
    for (int st = 32; st > 0; st >>= 1) {
        mxA = fmaxf(mxA, __shfl_down(mxA, st));
        mxB = fmaxf(mxB, __shfl_down(mxB, st));
    }
    if (lane == 0) { wmxA[w] = mxA; wmxB[w] = mxB; }
    __syncthreads();   // B1: keys + wave maxima ready
    const float MA = fmaxf(fmaxf(fmaxf(wmxA[0], wmxA[1]), fmaxf(wmxA[2], wmxA[3])),
                           fmaxf(fmaxf(wmxA[4], wmxA[5]), fmaxf(wmxA[6], wmxA[7])));
    const float MB = fmaxf(fmaxf(fmaxf(wmxB[0], wmxB[1]), fmaxf(wmxB[2], wmxB[3])),
                           fmaxf(fmaxf(wmxB[4], wmxB[5]), fmaxf(wmxB[6], wmxB[7])));

    // ---- window boundaries ONCE (key-determined, shared by both rows) ----
    int L8[4], R8[4];
    const int a = cb, b = cb + 3;
    {
        const int le = (rA - 1 < b) ? rA - 1 : b;
        if (a <= le) {
            const float da = key[a];
            const int Ra = bs_right(key, da, rA, NN);
            int Rl = Ra;
            if (le > a) Rl = bs_right(key, key[le], rA, Ra);
            for (int p = a; p <= le; ++p) {
                const float d = key[p];
                int R;
                if (p == a) R = Ra;
                else if (p == le) R = Rl;
                else R = bs_right(key, d, Rl, Ra);
                int L = p + 1;
                while (L < rA && key[L] == d) ++L;
                L8[p - a] = L; R8[p - a] = R;
            }
        }
        const int rs = (rA + 1 > a) ? rA + 1 : a;
        if (rs <= b) {
            const float dr = key[rs];
            const int Lr = bs_left(key, dr, 0, rA);
            int Lb = Lr;
            if (b > rs) Lb = bs_left(key, key[b], 0, Lr);
            for (int p = rs; p <= b; ++p) {
                const float d = key[p];
                int L;
                if (p == rs) L = Lr;
                else if (p == b) L = Lb;
                else L = bs_left(key, d, Lb, Lr);
                int R = p;
                while (R > rA && key[R - 1] == d) --R;
                L8[p - a] = L; R8[p - a] = R;
            }
        }
        if (rA >= a && rA <= b) { L8[rA - a] = rA; R8[rA - a] = rA; }
    }

    // ================= row A: scans + accumulate =================
    double lnsumA = 0.0;
    {
        float e8[4];
        #pragma unroll
        for (int jj = 0; jj < 4; ++jj) e8[jj] = __expf(vA[jj] - MA + CS);
        // prefix
        {
            float run = 0.f, ex[4];
            #pragma unroll
            for (int jj = 0; jj < 4; ++jj) { ex[jj] = run; run += e8[jj]; }
            float inc = run;
            #pragma unroll
            for (int st = 1; st < 64; st <<= 1) {
                const float nm = __shfl_up(inc, st);
                if (lane >= st) inc += nm;
            }
            float xofs = __shfl_up(inc, 1);
            if (lane == 0) xofs = 0.f;
            if (lane == 63) wps[w] = inc;
            __syncthreads();   // B2
            #pragma unroll
            for (int ww = 0; ww < 7; ++ww)
                if (ww < w) xofs += wps[ww];
            #pragma unroll
            for (int jj = 0; jj < 4; ++jj) Pf[cb + jj] = ex[jj] + xofs;
        }
        // suffix
        {
            float run = 0.f, sx[4];
            #pragma unroll
            for (int jj = 3; jj >= 0; --jj) { run += e8[jj]; sx[jj] = run; }
            float inc = run;
            #pragma unroll
            for (int st = 1; st < 64; st <<= 1) {
                const float nm = __shfl_down(inc, st);
                if (lane + st < 64) inc += nm;
            }
            float xofs = __shfl_down(inc, 1);
            if (lane == 63) xofs = 0.f;
            if (lane == 0) wss[w] = inc;
            __syncthreads();   // B3
            #pragma unroll
            for (int ww = 1; ww < 8; ++ww)
                if (ww > w) xofs += wss[ww];
            #pragma unroll
            for (int jj = 0; jj < 4; ++jj) Sf[cb + jj] = sx[jj] + xofs;
            if (t == 0) Sf[NN] = 0.f;
        }
        __syncthreads();   // B4: Pf/Sf(A) ready
        const float MBA = MA - CS;
        #pragma unroll
        for (int jj = 0; jj < 4; ++jj) {
            const int p = cb + jj;
            if (p == rA) continue;
            const float s = fmaxf(Pf[L8[jj]] + Sf[R8[jj]], 1e-38f);
            lnsumA += (double)(MBA + __logf(s));
        }
    }
    __syncthreads();   // B5: done reading Pf/Sf(A)

    // ================= row B: scans + accumulate =================
    double lnsumB = 0.0;
    {
        float e8[4];
        #pragma unroll
        for (int jj = 0; jj < 4; ++jj) e8[jj] = __expf(vB[jj] - MB + CS);
        {
            float run = 0.f, ex[4];
            #pragma unroll
            for (int jj = 0; jj < 4; ++jj) { ex[jj] = run; run += e8[jj]; }
            float inc = run;
            #pragma unroll
            for (int st = 1; st < 64; st <<= 1) {
                const float nm = __shfl_up(inc, st);
                if (lane >= st) inc += nm;
            }
            float xofs = __shfl_up(inc, 1);
            if (lane == 0) xofs = 0.f;
            if (lane == 63) wps[w] = inc;
            __syncthreads();   // B6
            #pragma unroll
            for (int ww = 0; ww < 7; ++ww)
                if (ww < w) xofs += wps[ww];
            #pragma unroll
            for (int jj = 0; jj < 4; ++jj) Pf[cb + jj] = ex[jj] + xofs;
        }
        {
            float run = 0.f, sx[4];
            #pragma unroll
            for (int jj = 3; jj >= 0; --jj) { run += e8[jj]; sx[jj] = run; }
            float inc = run;
            #pragma unroll
            for (int st = 1; st < 64; st <<= 1) {
                const float nm = __shfl_down(inc, st);
                if (lane + st < 64) inc += nm;
            }
            float xofs = __shfl_down(inc, 1);
            if (lane == 63) xofs = 0.f;
            if (lane == 0) wss[w] = inc;
            __syncthreads();   // B7
            #pragma unroll
            for (int ww = 1; ww < 8; ++ww)
                if (ww > w) xofs += wss[ww];
            #pragma unroll
            for (int jj = 0; jj < 4; ++jj) Sf[cb + jj] = sx[jj] + xofs;
            if (t == 0) Sf[NN] = 0.f;
        }
        __syncthreads();   // B8: Pf/Sf(B) ready
        const float MBB = MB - CS;
        #pragma unroll
        for (int jj = 0; jj < 4; ++jj) {
            const int p = cb + jj;
            if (p == rB) continue;
            const float s = fmaxf(Pf[L8[jj]] + Sf[R8[jj]], 1e-38f);
            lnsumB += (double)(MBB + __logf(s));
        }
    }

    // ---- reductions (both rows) ----
    #pragma unroll
    for (int st = 32; st > 0; st >>= 1) {
        dsumA  += __shfl_down(dsumA, st);
        lnsumA += __shfl_down(lnsumA, st);
        dsumB  += __shfl_down(dsumB, st);
        lnsumB += __shfl_down(lnsumB, st);
    }
    if (lane == 0) { wDA[w] = dsumA; wLA[w] = lnsumA; wDB[w] = dsumB; wLB[w] = lnsumB; }
    __syncthreads();   // B9
    if (t == 0) {
        double dA = 0.0, lA = 0.0, dB = 0.0, lB = 0.0;
        #pragma unroll
        for (int ww = 0; ww < 8; ++ww) { dA += wDA[ww]; lA += wLA[ww]; dB += wDB[ww]; lB += wLB[ww]; }
        rowval[rA] = (-dA / 0.07) - lA;
        rowval[rB] = (-dB / 0.07) - lB;
    }
}

// ---------------- kernel 3: final mean ----------------
__global__ __launch_bounds__(256) void finalize_kernel(const double* __restrict__ rowval,
                                                       float* __restrict__ out) {
    __shared__ double red[NT];
    const int t = threadIdx.x;
    double s = 0.0;
    for (int j = t; j < NN; j += NT) s += rowval[j];
    red[t] = s;
    __syncthreads();
    for (int ofs = NT / 2; ofs > 0; ofs >>= 1) {
        if (t < ofs) red[t] += red[t + ofs];
        __syncthreads();
    }
    if (t == 0) {
        out[0] = (float)(-red[0] / ((double)NN * (double)(NN - 1)));
    }
}

extern "C" void kernel_launch(void* const* d_in, const int* in_sizes, int n_in,
                              void* d_out, int out_size, void* d_ws, size_t ws_size,
                              hipStream_t stream) {
    const float* features = (const float*)d_in[0];  // [1024, 2, 512] fp32
    const float* labels   = (const float*)d_in[1];  // [1024] fp32
    float* out = (float*)d_out;

    char* ws = (char*)d_ws;
    size_t off = 0;
    float*  sq     = (float*) (ws + off); off += NN * sizeof(float);
    float*  slab   = (float*) (ws + off); off += NN * sizeof(float);
    int*    sj     = (int*)   (ws + off); off += NN * sizeof(int);
    double* rowval = (double*)(ws + off); off += NN * sizeof(double);
    ushort* Ahi    = (ushort*)(ws + off); off += (size_t)NN * DD * sizeof(ushort);
    ushort* Alo    = (ushort*)(ws + off); off += (size_t)NN * DD * sizeof(ushort);
    float*  distp  = (float*) (ws + off); off += (size_t)NN * NN * sizeof(float);

    prep_sort_kernel<<<258, 512, 0, stream>>>(features, labels, Ahi, Alo, sq, slab, sj);
    gemm_dist_kernel<<<528, NT, 0, stream>>>(Ahi, Alo, sq, sj, distp);  // 32*33/2 lower tiles
    row_kernel<<<NN / 2, 512, 0, stream>>>(distp, slab, rowval);
    finalize_kernel<<<1, NT, 0, stream>>>(rowval, out);
}